// Round 1
// baseline (1549.082 us; speedup 1.0000x reference)
//
#include <hip/hip_runtime.h>
#include <cstddef>

#define SEQ 256
#define BATCH 32
#define REC 16
#define EMB 32
#define VOC 32000
#define NROW (SEQ*BATCH)   // 8192 rows of (t,b)

// ---------------------------------------------------------------------------
// K0: a[row][r] = bias1[r] + sum_e emb[idx[row]][e] * U[r][e]
// row = t*32+b (input_batch is [S][B] row-major). Fully parallel.
// ---------------------------------------------------------------------------
__global__ __launch_bounds__(256) void embed_proj(
    const int* __restrict__ idx, const float* __restrict__ emb,
    const float* __restrict__ U, const float* __restrict__ b1,
    float* __restrict__ a) {
  __shared__ float Us[REC * EMB];
  __shared__ float b1s[REC];
  int tid = threadIdx.x;
  Us[tid]       = U[tid];
  Us[tid + 256] = U[tid + 256];
  if (tid < REC) b1s[tid] = b1[tid];
  __syncthreads();
  int gid = blockIdx.x * 256 + tid;      // 0..131071
  int row = gid >> 4;
  int r   = gid & 15;
  const float* ep = emb + (size_t)idx[row] * EMB;
  const float* up = Us + r * EMB;
  float p0 = 0.f, p1 = 0.f, p2 = 0.f, p3 = 0.f;
#pragma unroll
  for (int e = 0; e < EMB; e += 4) {
    p0 = fmaf(ep[e],     up[e],     p0);
    p1 = fmaf(ep[e + 1], up[e + 1], p1);
    p2 = fmaf(ep[e + 2], up[e + 2], p2);
    p3 = fmaf(ep[e + 3], up[e + 3], p3);
  }
  a[gid] = b1s[r] + ((p0 + p1) + (p2 + p3));
}

// ---------------------------------------------------------------------------
// K1: sequential recurrence. 8 blocks x 64 threads (1 wave). Each block owns
// 4 independent batch chains (lane = c*16+r, c=chain, r=state index).
// State prev = h[b][r] lives in a register; cross-lane h[j] via __shfl
// (wave-lockstep: all shuffles of iteration t read pre-update prev).
// hidden[t] = state BEFORE step t (matches the reference scan output).
// 'a' is staged into LDS up front so the serial loop never touches HBM reads.
// ---------------------------------------------------------------------------
__global__ __launch_bounds__(64) void rnn_rec(
    const float* __restrict__ a, const float* __restrict__ W,
    const float* __restrict__ b2, const float* __restrict__ h0,
    float* __restrict__ hidden) {
  __shared__ float als[SEQ * 64];        // 64 KB: this block's a-slice
  int tid = threadIdx.x;                 // 0..63
  int r   = tid & 15;
  int b0  = blockIdx.x * 4;
  // stage a[t][b0*16 .. b0*16+63] for all t, as float4s
  for (int i = 0; i < 64; i++) {
    int k = i * 64 + tid;                // 0..4095
    int t = k >> 4;
    int q = (k & 15) * 4;
    *(float4*)&als[t * 64 + q] = *(const float4*)(a + t * 512 + b0 * 16 + q);
  }
  float w[16];
#pragma unroll
  for (int j = 0; j < 16; j++) w[j] = W[r * 16 + j];
  float bias = b2[r];
  float prev = h0[r];
  int base = tid & 48;                   // chain's lane base
  __syncthreads();                       // fence staging writes vs reads (once)
  for (int t = 0; t < SEQ; t++) {
    hidden[t * 512 + b0 * 16 + tid] = prev;   // h BEFORE this step
    float cura = als[t * 64 + tid];
    float p0 = 0.f, p1 = 0.f, p2 = 0.f, p3 = 0.f;
#pragma unroll
    for (int j = 0; j < 4; j++) p0 = fmaf(__shfl(prev, base + j,      64), w[j],      p0);
#pragma unroll
    for (int j = 0; j < 4; j++) p1 = fmaf(__shfl(prev, base + 4 + j,  64), w[4 + j],  p1);
#pragma unroll
    for (int j = 0; j < 4; j++) p2 = fmaf(__shfl(prev, base + 8 + j,  64), w[8 + j],  p2);
#pragma unroll
    for (int j = 0; j < 4; j++) p3 = fmaf(__shfl(prev, base + 12 + j, 64), w[12 + j], p3);
    float acc = cura + bias + ((p0 + p1) + (p2 + p3));
    // tanh(x) = (e^{2x}-1)/(e^{2x}+1); |acc| <= ~7 so no overflow
    float e = __expf(2.0f * acc);
    prev = __fdividef(e - 1.0f, e + 1.0f);
  }
}

// ---------------------------------------------------------------------------
// K2: fused logits + log_softmax. One wave per 4 rows; each lane holds the 4
// h-rows (64 regs) and streams V (L2-resident) with 1-deep register prefetch.
// |logit| <= 4 -> skip max subtraction: pass1 sums exp(logit); pass2
// recomputes logits and writes logit - log(sum). Writes are the HBM floor.
// ---------------------------------------------------------------------------
__device__ __forceinline__ float dot16(const float* h, float4 c0, float4 c1,
                                       float4 c2, float4 c3) {
  float p0 = fmaf(h[0],  c0.x, fmaf(h[1],  c0.y, fmaf(h[2],  c0.z, h[3]  * c0.w)));
  float p1 = fmaf(h[4],  c1.x, fmaf(h[5],  c1.y, fmaf(h[6],  c1.z, h[7]  * c1.w)));
  float p2 = fmaf(h[8],  c2.x, fmaf(h[9],  c2.y, fmaf(h[10], c2.z, h[11] * c2.w)));
  float p3 = fmaf(h[12], c3.x, fmaf(h[13], c3.y, fmaf(h[14], c3.z, h[15] * c3.w)));
  return (p0 + p1) + (p2 + p3);
}

__global__ __launch_bounds__(256, 2) void logits_lsm(
    const float* __restrict__ hidden, const float* __restrict__ Vm,
    float* __restrict__ out) {
  int tid  = threadIdx.x;
  int lane = tid & 63;
  int g    = tid >> 6;                   // wave id = row group
  int row0 = blockIdx.x * 16 + g * 4;    // this wave's 4 rows
  float hr[4][16];
#pragma unroll
  for (int i = 0; i < 4; i++) {
    const float4* hp = (const float4*)(hidden + (size_t)(row0 + i) * REC);
    float4 x0 = hp[0], x1 = hp[1], x2 = hp[2], x3 = hp[3];
    hr[i][0] = x0.x;  hr[i][1] = x0.y;  hr[i][2] = x0.z;  hr[i][3] = x0.w;
    hr[i][4] = x1.x;  hr[i][5] = x1.y;  hr[i][6] = x1.z;  hr[i][7] = x1.w;
    hr[i][8] = x2.x;  hr[i][9] = x2.y;  hr[i][10] = x2.z; hr[i][11] = x2.w;
    hr[i][12] = x3.x; hr[i][13] = x3.y; hr[i][14] = x3.z; hr[i][15] = x3.w;
  }
  const float4* Vp = (const float4*)Vm;
  float lsum[4] = {0.f, 0.f, 0.f, 0.f};
  float4 n0, n1, n2, n3;
  {
    size_t vb = (size_t)lane * 4;
    n0 = Vp[vb]; n1 = Vp[vb + 1]; n2 = Vp[vb + 2]; n3 = Vp[vb + 3];
  }
  // ---- pass 1: sum of exp(logit) over vocab ----
  for (int i = 0; i < 500; i++) {
    float4 c0 = n0, c1 = n1, c2 = n2, c3 = n3;
    if (i < 499) {
      size_t vb = (size_t)(lane + 64 * (i + 1)) * 4;
      n0 = Vp[vb]; n1 = Vp[vb + 1]; n2 = Vp[vb + 2]; n3 = Vp[vb + 3];
    }
#pragma unroll
    for (int rr = 0; rr < 4; rr++)
      lsum[rr] += __expf(dot16(hr[rr], c0, c1, c2, c3));
  }
  float logl[4];
#pragma unroll
  for (int rr = 0; rr < 4; rr++) {
    float s = lsum[rr];
#pragma unroll
    for (int off = 32; off; off >>= 1) s += __shfl_xor(s, off, 64);
    logl[rr] = __logf(s);                // butterfly => all lanes have total
  }
  // ---- pass 2: recompute logits, write normalized ----
  {
    size_t vb = (size_t)lane * 4;
    n0 = Vp[vb]; n1 = Vp[vb + 1]; n2 = Vp[vb + 2]; n3 = Vp[vb + 3];
  }
  for (int i = 0; i < 500; i++) {
    int v = lane + 64 * i;
    float4 c0 = n0, c1 = n1, c2 = n2, c3 = n3;
    if (i < 499) {
      size_t vb = (size_t)(v + 64) * 4;
      n0 = Vp[vb]; n1 = Vp[vb + 1]; n2 = Vp[vb + 2]; n3 = Vp[vb + 3];
    }
#pragma unroll
    for (int rr = 0; rr < 4; rr++)
      out[(size_t)(row0 + rr) * VOC + v] = dot16(hr[rr], c0, c1, c2, c3) - logl[rr];
  }
}

// ---------------------------------------------------------------------------
extern "C" void kernel_launch(void* const* d_in, const int* in_sizes, int n_in,
                              void* d_out, int out_size, void* d_ws, size_t ws_size,
                              hipStream_t stream) {
  const int*   idx = (const int*)d_in[0];    // [256][32]
  const float* emb = (const float*)d_in[1];  // [32000][32]
  const float* U   = (const float*)d_in[2];  // [16][32]
  const float* W   = (const float*)d_in[3];  // [16][16]
  const float* V   = (const float*)d_in[4];  // [32000][16]
  const float* b1  = (const float*)d_in[5];  // [16]
  const float* b2  = (const float*)d_in[6];  // [16]
  const float* h0  = (const float*)d_in[7];  // [16]
  float* out = (float*)d_out;                // [256][32][32000]

  float* a      = (float*)d_ws;              // [8192][16] = 512 KB
  float* hidden = a + (size_t)NROW * REC;    // [8192][16] = 512 KB

  embed_proj<<<NROW * REC / 256, 256, 0, stream>>>(idx, emb, U, b1, a);
  rnn_rec<<<BATCH / 4, 64, 0, stream>>>(a, W, b2, h0, hidden);
  logits_lsm<<<NROW / 16, 256, 0, stream>>>(hidden, V, out);
}